// Round 4
// baseline (426.258 us; speedup 1.0000x reference)
//
#include <hip/hip_runtime.h>
#include <math.h>

#define BSZ 128
#define KTOT 196608            // 3*256*256
#define NBLK1 512              // split-K blocks (2 per CU)
#define KC (KTOT / NBLK1)      // 384
#define BK 32                  // k per slab
#define NSLAB (KC / BK)        // 12
#define RS 40                  // LDS row stride in bf16 (32 + 8 pad)
#define REGF 0.01f
#define NITER 8                // contraction ~0.02/iter; converged ~1e-13

typedef short bf16x8 __attribute__((ext_vector_type(8)));
typedef float f32x4 __attribute__((ext_vector_type(4)));

__device__ __forceinline__ unsigned short f2bf(float f) {
    union { float f; unsigned int u; } x; x.f = f;
    unsigned int r = x.u + 0x7fffu + ((x.u >> 16) & 1u);   // RNE
    return (unsigned short)(r >> 16);
}

__global__ void zero_kernel(float* p, int n) {
    int i = blockIdx.x * blockDim.x + threadIdx.x;
    if (i < n) p[i] = 0.f;
}

// Split-K bf16-MFMA GEMM, single-barrier double-buffered LDS + depth-2
// register prefetch. Block b covers a 384-long K-chunk; stores its 128x128
// partial TRANSPOSED (P[part][col*128+row]) so the MFMA C/D fragment
// (col=lane&15, row=quad*4+reg) is a contiguous f32x4 store.
__global__ __launch_bounds__(256, 2) void dot_kernel(
    const float* __restrict__ imgs, const float* __restrict__ imgs_w,
    const float* __restrict__ target, float* __restrict__ P,
    float* __restrict__ x2, float* __restrict__ y2)
{
    __shared__ unsigned short Abf[2][BSZ * RS];   // delta, [row][k]
    __shared__ unsigned short Bbf[2][BSZ * RS];   // target
    __shared__ float x2s[BSZ], y2s[BSZ];
    const int t = threadIdx.x;
    const int bid = blockIdx.x;
    const long kbase = (long)bid * KC;
    if (t < BSZ) { x2s[t] = 0.f; y2s[t] = 0.f; }

    const int lane = t & 63;
    const int wv = t >> 6;
    const int fr = lane & 15;     // fragment col within 16-tile
    const int fq = lane >> 4;     // quad
    const int wrow0 = wv * 32;    // wave's output-row block
    const int f4 = t & 7;
    const int rbase = t >> 3;

    f32x4 acc[2][8];
#pragma unroll
    for (int rt = 0; rt < 2; ++rt)
#pragma unroll
        for (int ct = 0; ct < 8; ++ct) acc[rt][ct] = (f32x4){0.f, 0.f, 0.f, 0.f};
    float x2p[4] = {0.f, 0.f, 0.f, 0.f};
    float y2p[4] = {0.f, 0.f, 0.f, 0.f};

    long gq[4];
#pragma unroll
    for (int q = 0; q < 4; ++q)
        gq[q] = (long)(32 * q + rbase) * KTOT + kbase + f4 * 4;

    float4 rw[2][4], ri[2][4], rt4[2][4];
    // prologue: slab 0 -> set 0, slab 1 -> set 1, stage slab 0 into buf 0
#pragma unroll
    for (int q = 0; q < 4; ++q) {
        rw[0][q]  = *(const float4*)(imgs_w + gq[q]);
        ri[0][q]  = *(const float4*)(imgs + gq[q]);
        rt4[0][q] = *(const float4*)(target + gq[q]);
    }
#pragma unroll
    for (int q = 0; q < 4; ++q) {
        rw[1][q]  = *(const float4*)(imgs_w + gq[q] + BK);
        ri[1][q]  = *(const float4*)(imgs + gq[q] + BK);
        rt4[1][q] = *(const float4*)(target + gq[q] + BK);
    }
#pragma unroll
    for (int q = 0; q < 4; ++q) {
        const float d0 = rw[0][q].x - ri[0][q].x, d1 = rw[0][q].y - ri[0][q].y;
        const float d2 = rw[0][q].z - ri[0][q].z, d3 = rw[0][q].w - ri[0][q].w;
        const float b0 = rt4[0][q].x, b1 = rt4[0][q].y, b2 = rt4[0][q].z, b3 = rt4[0][q].w;
        x2p[q] += d0 * d0 + d1 * d1 + d2 * d2 + d3 * d3;
        y2p[q] += b0 * b0 + b1 * b1 + b2 * b2 + b3 * b3;
        const int idx = (32 * q + rbase) * RS + f4 * 4;
        ushort4 pa; pa.x = f2bf(d0); pa.y = f2bf(d1); pa.z = f2bf(d2); pa.w = f2bf(d3);
        ushort4 pb; pb.x = f2bf(b0); pb.y = f2bf(b1); pb.z = f2bf(b2); pb.w = f2bf(b3);
        *(ushort4*)&Abf[0][idx] = pa;
        *(ushort4*)&Bbf[0][idx] = pb;
    }
    __syncthreads();

    for (int s = 0; s < NSLAB; ++s) {
        const int cur = s & 1;
        const int nxt = cur ^ 1;
        // 1) issue loads for slab s+2 into the just-freed set (gap = 1 full slab)
        if (s + 2 < NSLAB) {
            const long ko = (long)(s + 2) * BK;
#pragma unroll
            for (int q = 0; q < 4; ++q) {
                rw[cur][q]  = *(const float4*)(imgs_w + gq[q] + ko);
                ri[cur][q]  = *(const float4*)(imgs + gq[q] + ko);
                rt4[cur][q] = *(const float4*)(target + gq[q] + ko);
            }
        }
        // 2) stage slab s+1 into buf nxt (its readers finished before last barrier)
        if (s + 1 < NSLAB) {
#pragma unroll
            for (int q = 0; q < 4; ++q) {
                const float d0 = rw[nxt][q].x - ri[nxt][q].x, d1 = rw[nxt][q].y - ri[nxt][q].y;
                const float d2 = rw[nxt][q].z - ri[nxt][q].z, d3 = rw[nxt][q].w - ri[nxt][q].w;
                const float b0 = rt4[nxt][q].x, b1 = rt4[nxt][q].y;
                const float b2 = rt4[nxt][q].z, b3 = rt4[nxt][q].w;
                x2p[q] += d0 * d0 + d1 * d1 + d2 * d2 + d3 * d3;
                y2p[q] += b0 * b0 + b1 * b1 + b2 * b2 + b3 * b3;
                const int idx = (32 * q + rbase) * RS + f4 * 4;
                ushort4 pa; pa.x = f2bf(d0); pa.y = f2bf(d1); pa.z = f2bf(d2); pa.w = f2bf(d3);
                ushort4 pb; pb.x = f2bf(b0); pb.y = f2bf(b1); pb.z = f2bf(b2); pb.w = f2bf(b3);
                *(ushort4*)&Abf[nxt][idx] = pa;
                *(ushort4*)&Bbf[nxt][idx] = pb;
            }
        }
        // 3) MFMA on buf cur (staged last iteration, published by the barrier)
        const bf16x8 a0 = *(const bf16x8*)&Abf[cur][(wrow0 + fr) * RS + fq * 8];
        const bf16x8 a1 = *(const bf16x8*)&Abf[cur][(wrow0 + 16 + fr) * RS + fq * 8];
#pragma unroll
        for (int ct = 0; ct < 8; ++ct) {
            const bf16x8 b = *(const bf16x8*)&Bbf[cur][(ct * 16 + fr) * RS + fq * 8];
            acc[0][ct] = __builtin_amdgcn_mfma_f32_16x16x32_bf16(a0, b, acc[0][ct], 0, 0, 0);
            acc[1][ct] = __builtin_amdgcn_mfma_f32_16x16x32_bf16(a1, b, acc[1][ct], 0, 0, 0);
        }
        __syncthreads();
    }

    // norms: LDS combine, then 256 global atomics per block (off critical path)
#pragma unroll
    for (int q = 0; q < 4; ++q) {
        atomicAdd(&x2s[32 * q + rbase], x2p[q]);
        atomicAdd(&y2s[32 * q + rbase], y2p[q]);
    }
    __syncthreads();
    if (t < BSZ) {
        atomicAdd(&x2[t], x2s[t]);
        atomicAdd(&y2[t], y2s[t]);
    }

    // transposed partial store: P[bid][ (ct*16+fr)*128 + wrow0 + rt*16 + fq*4 .. +3 ]
    float* Pb = P + ((size_t)bid << 14);
#pragma unroll
    for (int rt = 0; rt < 2; ++rt)
#pragma unroll
        for (int ct = 0; ct < 8; ++ct)
            *(f32x4*)&Pb[(ct * 16 + fr) * BSZ + wrow0 + rt * 16 + fq * 4] = acc[rt][ct];
}

// Sum 512 partials per output position; build CT[j*128+i] = C[i][j].
// Sinkhorn on C^T is output-identical (a=b=uniform -> u,v swap roles).
__global__ __launch_bounds__(256) void reduce_kernel(
    const float* __restrict__ P, const float* __restrict__ x2,
    const float* __restrict__ y2, float* __restrict__ CT)
{
    __shared__ float red[4][64];
    const int t = threadIdx.x;
    const int b = blockIdx.x;
    const int o = t & 63;
    const int g = t >> 6;              // 4 part-groups x 128 parts
    const int pos = b * 64 + o;
    float a[16];
#pragma unroll
    for (int m = 0; m < 16; ++m) a[m] = 0.f;
    for (int m0 = 0; m0 < 128; m0 += 16) {
#pragma unroll
        for (int m = 0; m < 16; ++m)
            a[m] += P[(size_t)(g * 128 + m0 + m) * 16384 + pos];
    }
    float s = 0.f;
#pragma unroll
    for (int m = 0; m < 16; ++m) s += a[m];
    red[g][o] = s;
    __syncthreads();
    if (t < 64) {
        const float stot = red[0][t] + red[1][t] + red[2][t] + red[3][t];
        const int p = b * 64 + t;
        const int row = p & 127;       // i (delta index)
        const int col = p >> 7;        // j (target index)
        CT[p] = sqrtf(fmaxf(x2[row] + y2[col] - 2.f * stot, 0.f));
    }
}

// Single-block sinkhorn; exp-factorized (two 128x128 matvecs per iteration).
__global__ __launch_bounds__(1024) void sinkhorn_kernel(
    const float* __restrict__ Cg, float* __restrict__ out)
{
    __shared__ float C_lds[BSZ * BSZ];
    __shared__ float w_s[BSZ];
    __shared__ float g_s[BSZ];
    __shared__ float u_s[BSZ], v_s[BSZ];
    const int t = threadIdx.x;
    const int lane = t & 63;
    const int wave = t >> 6;
    const int rgrp = wave * 8 + (lane >> 3);
    const int off16 = (lane & 7) * 16;

#pragma unroll
    for (int q = 0; q < 4; ++q)
        *(float4*)&C_lds[q * 4096 + t * 4] = *(const float4*)&Cg[q * 4096 + t * 4];
    if (t < BSZ) w_s[t] = 1.f;
    __syncthreads();

    float rowE[16], colF[16], mrow, mcol;
    {
        float tmp[16]; float m = -1e30f;
#pragma unroll
        for (int k = 0; k < 16; ++k) { tmp[k] = C_lds[rgrp * BSZ + off16 + k]; m = fmaxf(m, tmp[k]); }
        m = fmaxf(m, __shfl_xor(m, 1)); m = fmaxf(m, __shfl_xor(m, 2)); m = fmaxf(m, __shfl_xor(m, 4));
        mrow = m;
#pragma unroll
        for (int k = 0; k < 16; ++k) rowE[k] = __expf(tmp[k] - mrow);
    }
    {
        float tmp[16]; float m = -1e30f;
#pragma unroll
        for (int k = 0; k < 16; ++k) { tmp[k] = C_lds[(off16 + k) * BSZ + rgrp]; m = fmaxf(m, tmp[k]); }
        m = fmaxf(m, __shfl_xor(m, 1)); m = fmaxf(m, __shfl_xor(m, 2)); m = fmaxf(m, __shfl_xor(m, 4));
        mcol = m;
#pragma unroll
        for (int k = 0; k < 16; ++k) colF[k] = __expf(tmp[k] - mcol);
    }

    const float log_ab = -logf(128.f);
    float u_cur = 0.f, v_cur = 0.f;

    for (int it = 0; it < NITER; ++it) {
        float acc = 0.f;
#pragma unroll
        for (int k = 0; k < 16; ++k) acc += rowE[k] * w_s[off16 + k];
        acc += __shfl_xor(acc, 1); acc += __shfl_xor(acc, 2); acc += __shfl_xor(acc, 4);
        const float lse = mrow + __logf(acc);
        u_cur = REGF * (log_ab - lse + u_cur);
        if ((lane & 7) == 0) g_s[rgrp] = __expf(-u_cur);
        __syncthreads();
        float acc2 = 0.f;
#pragma unroll
        for (int k = 0; k < 16; ++k) acc2 += colF[k] * g_s[off16 + k];
        acc2 += __shfl_xor(acc2, 1); acc2 += __shfl_xor(acc2, 2); acc2 += __shfl_xor(acc2, 4);
        const float lse2 = mcol + __logf(acc2);
        v_cur = REGF * (log_ab - lse2 + v_cur);
        if ((lane & 7) == 0) w_s[rgrp] = __expf(-v_cur);
        __syncthreads();
    }

    if ((lane & 7) == 0) { u_s[rgrp] = u_cur; v_s[rgrp] = v_cur; }
    __syncthreads();
    if (t == 0) {
        float su = 0.f;
        for (int i = 0; i < BSZ; ++i) su += u_s[i] + v_s[i];
        out[0] = su / 128.f;
    }
}

extern "C" void kernel_launch(void* const* d_in, const int* in_sizes, int n_in,
                              void* d_out, int out_size, void* d_ws, size_t ws_size,
                              hipStream_t stream) {
    const float* imgs   = (const float*)d_in[0];
    const float* imgs_w = (const float*)d_in[1];
    const float* target = (const float*)d_in[2];
    float* out = (float*)d_out;
    float* wsf = (float*)d_ws;

    float* P  = wsf;                                  // 512 * 16384 partials
    float* x2 = wsf + (size_t)NBLK1 * BSZ * BSZ;      // 128
    float* y2 = x2 + BSZ;                             // 128
    float* CT = y2 + BSZ;                             // 128 * 128 (transposed C)

    zero_kernel<<<1, 256, 0, stream>>>(x2, 2 * BSZ);
    dot_kernel<<<NBLK1, 256, 0, stream>>>(imgs, imgs_w, target, P, x2, y2);
    reduce_kernel<<<BSZ * BSZ / 64, 256, 0, stream>>>(P, x2, y2, CT);
    sinkhorn_kernel<<<1, 1024, 0, stream>>>(CT, out);
}